// Round 4
// baseline (49.731 us; speedup 1.0000x reference)
//
#include <hip/hip_runtime.h>

// Problem constants (from reference): B=32, K=8, H=240, W=320
constexpr int B_  = 32;
constexpr int K_  = 8;
constexpr int H_  = 240;
constexpr int W_  = 320;
constexpr int HW  = H_ * W_;     // 76800
constexpr int NQ  = HW / 4;      // 19200 float4 quads per plane
constexpr int TPB = 256;         // threads per block
constexpr int BPB = NQ / TPB;    // 75 blocks per batch -> grid 2400, 1 quad/thread

// loss = 0.5 * sum_b (1/numpts[b]) * sum_{i,h,w} err^2
// pred[b,i,hw] = sum_k m[b,k,hw] * ( R[b,k,i,:]·p[b,:,hw] + t[b,k,i] )
__global__ __launch_bounds__(TPB, 4)
void w3d_loss_kernel(const float* __restrict__ pts,
                     const float* __restrict__ masks,
                     const float* __restrict__ tfms,
                     const float* __restrict__ tgt,
                     const float* __restrict__ numpts,
                     float* __restrict__ out)
{
    const int b = blockIdx.x / BPB;
    const int q = (blockIdx.x % BPB) * TPB + (int)threadIdx.x;  // < NQ by construction

    const float4* Px = (const float4*)(pts + (size_t)b * 3 * HW);
    const float4* Py = Px + NQ;
    const float4* Pz = Py + NQ;
    const float4* Tx = (const float4*)(tgt + (size_t)b * 3 * HW);
    const float4* Ty = Tx + NQ;
    const float4* Tz = Ty + NQ;
    const float4* Mb = (const float4*)(masks + (size_t)b * K_ * HW);
    const float*  tf = tfms + (size_t)b * K_ * 12;   // wave-uniform -> s_load

    // ---- Issue ALL 14 dwordx4 loads, in the order they will be consumed ----
    const float4 p4x = Px[q];
    const float4 p4y = Py[q];
    const float4 p4z = Pz[q];
    float4 m4[K_];
    #pragma unroll
    for (int k = 0; k < K_; ++k) m4[k] = Mb[(size_t)k * NQ + q];
    const float4 t4x = Tx[q];
    const float4 t4y = Ty[q];
    const float4 t4z = Tz[q];

    // Scheduling wall: nothing crosses. All 14 load destinations stay live,
    // so the hardware keeps 14 loads in flight and waitcnts unwind
    // progressively (px waits vmcnt(13), ..., tz waits vmcnt(0)).
    __builtin_amdgcn_sched_barrier(0);

    const float px[4] = {p4x.x, p4x.y, p4x.z, p4x.w};
    const float py[4] = {p4y.x, p4y.y, p4y.z, p4y.w};
    const float pz[4] = {p4z.x, p4z.y, p4z.z, p4z.w};

    float prx[4] = {0.f, 0.f, 0.f, 0.f};
    float pry[4] = {0.f, 0.f, 0.f, 0.f};
    float prz[4] = {0.f, 0.f, 0.f, 0.f};

    #pragma unroll
    for (int k = 0; k < K_; ++k) {
        const float f0 = tf[k*12+0], f1 = tf[k*12+1], f2  = tf[k*12+2],  f3  = tf[k*12+3];
        const float f4 = tf[k*12+4], f5 = tf[k*12+5], f6  = tf[k*12+6],  f7  = tf[k*12+7];
        const float f8 = tf[k*12+8], f9 = tf[k*12+9], f10 = tf[k*12+10], f11 = tf[k*12+11];
        const float m[4] = {m4[k].x, m4[k].y, m4[k].z, m4[k].w};
        #pragma unroll
        for (int l = 0; l < 4; ++l) {
            const float vx = fmaf(f0, px[l], fmaf(f1, py[l], fmaf(f2,  pz[l], f3)));
            const float vy = fmaf(f4, px[l], fmaf(f5, py[l], fmaf(f6,  pz[l], f7)));
            const float vz = fmaf(f8, px[l], fmaf(f9, py[l], fmaf(f10, pz[l], f11)));
            prx[l] = fmaf(m[l], vx, prx[l]);
            pry[l] = fmaf(m[l], vy, pry[l]);
            prz[l] = fmaf(m[l], vz, prz[l]);
        }
    }

    const float ttx[4] = {t4x.x, t4x.y, t4x.z, t4x.w};
    const float tty[4] = {t4y.x, t4y.y, t4y.z, t4y.w};
    const float ttz[4] = {t4z.x, t4z.y, t4z.z, t4z.w};

    float acc = 0.0f;
    #pragma unroll
    for (int l = 0; l < 4; ++l) {
        const float ex = prx[l] - ttx[l];
        const float ey = pry[l] - tty[l];
        const float ez = prz[l] - ttz[l];
        acc = fmaf(ex, ex, acc);
        acc = fmaf(ey, ey, acc);
        acc = fmaf(ez, ez, acc);
    }

    // Wave-64 butterfly reduce
    #pragma unroll
    for (int off = 32; off > 0; off >>= 1)
        acc += __shfl_down(acc, off, 64);

    __shared__ float wsum[TPB / 64];
    const int wid  = threadIdx.x >> 6;
    const int lane = threadIdx.x & 63;
    if (lane == 0) wsum[wid] = acc;
    __syncthreads();

    if (threadIdx.x == 0) {
        float s = 0.f;
        #pragma unroll
        for (int w = 0; w < TPB / 64; ++w) s += wsum[w];
        atomicAdd(out, 0.5f * s / numpts[b]);
    }
}

extern "C" void kernel_launch(void* const* d_in, const int* in_sizes, int n_in,
                              void* d_out, int out_size, void* d_ws, size_t ws_size,
                              hipStream_t stream)
{
    const float* pts    = (const float*)d_in[0];
    const float* masks  = (const float*)d_in[1];
    const float* tfms   = (const float*)d_in[2];
    const float* tgt    = (const float*)d_in[3];
    const float* numpts = (const float*)d_in[4];
    float* out = (float*)d_out;

    // d_out is poisoned (0xAA) before timing and never re-poisoned between
    // replays; zero it every call so the atomics accumulate from 0.
    hipMemsetAsync(out, 0, sizeof(float) * out_size, stream);

    dim3 grid(B_ * BPB);
    dim3 block(TPB);
    w3d_loss_kernel<<<grid, block, 0, stream>>>(pts, masks, tfms, tgt, numpts, out);
}